// Round 1
// baseline (1371.286 us; speedup 1.0000x reference)
//
#include <hip/hip_runtime.h>
#include <cstddef>

// Problem constants (from reference: S=2048, B=2, E=1024, H=16, D=64)
#define S_LEN 2048
#define B_SZ  2
#define E_SZ  1024
#define H_NUM 16
#define D_HEAD 64
#define M_ROWS (S_LEN * B_SZ)   // 4096 rows for all GEMMs
#define NEG_BIG (-1e30f)

// ---------------------------------------------------------------------------
// GEMM: C = A @ W^T + bias.  A[M,K] row-major, W[N,K] row-major (so we read
// W[j,k] = row j contiguous in k — NT GEMM, both operands contiguous in K).
// MODE 0: C row-major [M,N]  (used for the output projection -> d_out)
// MODE 1: scatter C into [B,H,S,D] layout (used for Q/K/V projections)
//   row r = s*B + b ; col j = h*D + d ; idx = ((b*H+h)*S + s)*D + d
// Tile: 64x64 output per block, 256 threads (16x16), 4x4 per thread, K-tile 32.
// ---------------------------------------------------------------------------
template <int MODE>
__global__ __launch_bounds__(256) void gemm_xwT(
    const float* __restrict__ A, const float* __restrict__ W,
    const float* __restrict__ bias, float* __restrict__ C,
    int M, int N, int K)
{
    // Transposed LDS tiles [k][m] so the inner loop reads float4 along m/n.
    // Row stride 68 floats = 272 B (16B-aligned rows, bank shift of 4).
    __shared__ float As[32][68];
    __shared__ float Ws[32][68];

    const int t  = threadIdx.x;
    const int tx = t & 15;        // output column group
    const int ty = t >> 4;        // output row group
    const int m0 = blockIdx.x * 64;
    const int n0 = blockIdx.y * 64;

    float acc[4][4] = {};

    for (int kt = 0; kt < K; kt += 32) {
        // Stage A tile (64 rows x 32 k) and W tile (64 cols x 32 k): 512
        // float4 each, 2 per thread. Coalesced 128B row segments.
#pragma unroll
        for (int l = 0; l < 2; ++l) {
            const int f   = t + l * 256;
            const int row = f >> 3;           // 0..63
            const int kp4 = (f & 7) << 2;     // 0,4,...,28
            float4 av = *(const float4*)&A[(size_t)(m0 + row) * K + kt + kp4];
            As[kp4 + 0][row] = av.x; As[kp4 + 1][row] = av.y;
            As[kp4 + 2][row] = av.z; As[kp4 + 3][row] = av.w;
            float4 wv = *(const float4*)&W[(size_t)(n0 + row) * K + kt + kp4];
            Ws[kp4 + 0][row] = wv.x; Ws[kp4 + 1][row] = wv.y;
            Ws[kp4 + 2][row] = wv.z; Ws[kp4 + 3][row] = wv.w;
        }
        __syncthreads();

#pragma unroll
        for (int kk = 0; kk < 32; ++kk) {
            const float4 a4 = *(const float4*)&As[kk][ty * 4];
            const float4 b4 = *(const float4*)&Ws[kk][tx * 4];
            const float a[4] = {a4.x, a4.y, a4.z, a4.w};
            const float b[4] = {b4.x, b4.y, b4.z, b4.w};
#pragma unroll
            for (int i = 0; i < 4; ++i)
#pragma unroll
                for (int j = 0; j < 4; ++j)
                    acc[i][j] = fmaf(a[i], b[j], acc[i][j]);
        }
        __syncthreads();
    }

    // Epilogue: add bias, store (float4 along columns).
    float bv[4];
#pragma unroll
    for (int j = 0; j < 4; ++j) bv[j] = bias[n0 + tx * 4 + j];

    if (MODE == 0) {
#pragma unroll
        for (int i = 0; i < 4; ++i) {
            const int row = m0 + ty * 4 + i;
            float4 o;
            o.x = acc[i][0] + bv[0]; o.y = acc[i][1] + bv[1];
            o.z = acc[i][2] + bv[2]; o.w = acc[i][3] + bv[3];
            *(float4*)&C[(size_t)row * N + n0 + tx * 4] = o;
        }
    } else {
        // Scatter into [B,H,S,D]. The 64-col block is exactly one head.
        const int h = (n0 + tx * 4) >> 6;       // head for this col group
        const int d = (n0 + tx * 4) & 63;
#pragma unroll
        for (int i = 0; i < 4; ++i) {
            const int row = m0 + ty * 4 + i;
            const int s = row / B_SZ;
            const int b = row % B_SZ;
            float4 o;
            o.x = acc[i][0] + bv[0]; o.y = acc[i][1] + bv[1];
            o.z = acc[i][2] + bv[2]; o.w = acc[i][3] + bv[3];
            *(float4*)&C[(((size_t)(b * H_NUM + h)) * S_LEN + s) * D_HEAD + d] = o;
        }
    }
}

// ---------------------------------------------------------------------------
// Causal flash attention, fp32. One block per (q-tile of 64 rows, b*h).
// 256 threads = 16x16; each thread owns a 4x4 sub-tile of the 64x64 score
// tile and a 4(rows) x 4(d-cols) sub-tile of the output accumulator.
// Online softmax == reference max-shift softmax (exp f32, sum/div f32).
// Output written directly into [S,B,E] so the out-proj GEMM is plain NT.
// ---------------------------------------------------------------------------
__global__ __launch_bounds__(256) void attn_fwd(
    const float* __restrict__ qp, const float* __restrict__ kp,
    const float* __restrict__ vp, float* __restrict__ outp)
{
    __shared__ float Qs[64][68];  // [d][qi]   (transposed)
    __shared__ float Ks[64][68];  // [d][ki]   (transposed)
    __shared__ float Vs[64][68];  // [ki][d]   (natural)
    __shared__ float Ps[64][68];  // [ki][qi]  (transposed P for PV)

    const int t  = threadIdx.x;
    const int tx = t & 15;
    const int ty = t >> 4;
    const int qt = blockIdx.x;       // q tile index, 0..31
    const int bh = blockIdx.y;       // b*H + h, 0..31
    const int q0 = qt * 64;

    const size_t base = (size_t)bh * S_LEN * D_HEAD;
    const float* qb = qp + base;
    const float* kb = kp + base;
    const float* vb = vp + base;

    // Load Q tile transposed: 1024 float4, 4 per thread. Coalesced.
#pragma unroll
    for (int l = 0; l < 4; ++l) {
        const int f   = t + l * 256;
        const int row = f >> 4;          // 0..63
        const int dp  = (f & 15) << 2;   // 0..60
        float4 v = *(const float4*)&qb[(size_t)(q0 + row) * D_HEAD + dp];
        Qs[dp + 0][row] = v.x; Qs[dp + 1][row] = v.y;
        Qs[dp + 2][row] = v.z; Qs[dp + 3][row] = v.w;
    }

    float m_r[4], l_r[4], o[4][4];
#pragma unroll
    for (int i = 0; i < 4; ++i) {
        m_r[i] = NEG_BIG; l_r[i] = 0.0f;
#pragma unroll
        for (int j = 0; j < 4; ++j) o[i][j] = 0.0f;
    }

    const float scale = 0.125f;  // 1/sqrt(64)

    for (int ktile = 0; ktile <= qt; ++ktile) {
        const int k0 = ktile * 64;
        __syncthreads();  // protect Ks/Vs/Ps (and Qs on iter 0) from prior readers

        // Stage K (transposed) and V (natural) tiles.
#pragma unroll
        for (int l = 0; l < 4; ++l) {
            const int f   = t + l * 256;
            const int row = f >> 4;
            const int dp  = (f & 15) << 2;
            float4 kv = *(const float4*)&kb[(size_t)(k0 + row) * D_HEAD + dp];
            Ks[dp + 0][row] = kv.x; Ks[dp + 1][row] = kv.y;
            Ks[dp + 2][row] = kv.z; Ks[dp + 3][row] = kv.w;
            float4 vv = *(const float4*)&vb[(size_t)(k0 + row) * D_HEAD + dp];
            *(float4*)&Vs[row][dp] = vv;
        }
        __syncthreads();

        // ---- scores: s[i][j] = sum_d Q[qi][d] * K[ki][d] ----
        float s[4][4] = {};
#pragma unroll
        for (int d = 0; d < 64; ++d) {
            const float4 q4 = *(const float4*)&Qs[d][ty * 4];
            const float4 k4 = *(const float4*)&Ks[d][tx * 4];
            const float qa[4] = {q4.x, q4.y, q4.z, q4.w};
            const float ka[4] = {k4.x, k4.y, k4.z, k4.w};
#pragma unroll
            for (int i = 0; i < 4; ++i)
#pragma unroll
                for (int j = 0; j < 4; ++j)
                    s[i][j] = fmaf(qa[i], ka[j], s[i][j]);
        }

        // ---- scale + causal mask + row max ----
        float rm[4];
#pragma unroll
        for (int i = 0; i < 4; ++i) {
            rm[i] = NEG_BIG;
            const int qg = q0 + ty * 4 + i;
#pragma unroll
            for (int j = 0; j < 4; ++j) {
                const int kg = k0 + tx * 4 + j;
                s[i][j] *= scale;
                if (kg > qg) s[i][j] = NEG_BIG;
                rm[i] = fmaxf(rm[i], s[i][j]);
            }
        }
        // reduce max across the 16 lanes that share this row group
#pragma unroll
        for (int off = 1; off < 16; off <<= 1)
#pragma unroll
            for (int i = 0; i < 4; ++i)
                rm[i] = fmaxf(rm[i], __shfl_xor(rm[i], off, 64));

        float mn[4], sc[4];
#pragma unroll
        for (int i = 0; i < 4; ++i) {
            mn[i] = fmaxf(m_r[i], rm[i]);
            sc[i] = expf(m_r[i] - mn[i]);   // -1e30-0 underflows to 0; 0-0 -> 1
            m_r[i] = mn[i];
        }

        // ---- p = exp(s - m), explicitly zeroed where masked ----
        float rs[4] = {0.f, 0.f, 0.f, 0.f};
#pragma unroll
        for (int i = 0; i < 4; ++i) {
            const int qg = q0 + ty * 4 + i;
#pragma unroll
            for (int j = 0; j < 4; ++j) {
                const int kg = k0 + tx * 4 + j;
                const float p = (kg > qg) ? 0.0f : expf(s[i][j] - mn[i]);
                s[i][j] = p;
                rs[i] += p;
            }
        }
#pragma unroll
        for (int off = 1; off < 16; off <<= 1)
#pragma unroll
            for (int i = 0; i < 4; ++i)
                rs[i] += __shfl_xor(rs[i], off, 64);

#pragma unroll
        for (int i = 0; i < 4; ++i) {
            l_r[i] = l_r[i] * sc[i] + rs[i];
#pragma unroll
            for (int j = 0; j < 4; ++j) o[i][j] *= sc[i];
        }

        // ---- stage P transposed for the PV GEMM ----
#pragma unroll
        for (int i = 0; i < 4; ++i)
#pragma unroll
            for (int j = 0; j < 4; ++j)
                Ps[tx * 4 + j][ty * 4 + i] = s[i][j];
        __syncthreads();

        // ---- O += P^T-tile @ V-tile ----
#pragma unroll
        for (int kk = 0; kk < 64; ++kk) {
            const float4 p4 = *(const float4*)&Ps[kk][ty * 4];
            const float4 v4 = *(const float4*)&Vs[kk][tx * 4];
            const float pa[4] = {p4.x, p4.y, p4.z, p4.w};
            const float va[4] = {v4.x, v4.y, v4.z, v4.w};
#pragma unroll
            for (int i = 0; i < 4; ++i)
#pragma unroll
                for (int j = 0; j < 4; ++j)
                    o[i][j] = fmaf(pa[i], va[j], o[i][j]);
        }
    }

    // ---- epilogue: divide by row sum, write to [S,B,E] ----
    const int b = bh / H_NUM;
    const int h = bh % H_NUM;
#pragma unroll
    for (int i = 0; i < 4; ++i) {
        const int sg = q0 + ty * 4 + i;
        const float inv = 1.0f / l_r[i];
        float4 ov;
        ov.x = o[i][0] * inv; ov.y = o[i][1] * inv;
        ov.z = o[i][2] * inv; ov.w = o[i][3] * inv;
        *(float4*)&outp[((size_t)sg * B_SZ + b) * E_SZ + h * D_HEAD + tx * 4] = ov;
    }
}

// ---------------------------------------------------------------------------
extern "C" void kernel_launch(void* const* d_in, const int* in_sizes, int n_in,
                              void* d_out, int out_size, void* d_ws, size_t ws_size,
                              hipStream_t stream)
{
    const float* query = (const float*)d_in[0];
    const float* key   = (const float*)d_in[1];
    const float* value = (const float*)d_in[2];
    const float* Wq = (const float*)d_in[3];  const float* bq = (const float*)d_in[4];
    const float* Wk = (const float*)d_in[5];  const float* bk = (const float*)d_in[6];
    const float* Wv = (const float*)d_in[7];  const float* bv = (const float*)d_in[8];
    const float* Wo = (const float*)d_in[9];  const float* bo = (const float*)d_in[10];
    float* out = (float*)d_out;

    // Workspace: qp, kp, vp in [B,H,S,D]; ao in [S,B,E]. 16M floats = 64 MB.
    const size_t PLANE = (size_t)M_ROWS * E_SZ;  // 4,194,304
    float* ws = (float*)d_ws;
    float* qp = ws;
    float* kp = qp + PLANE;
    float* vp = kp + PLANE;
    float* ao = vp + PLANE;
    (void)ws_size; (void)in_sizes; (void)n_in; (void)out_size;

    const dim3 tb(256);
    const dim3 gb(M_ROWS / 64, E_SZ / 64);   // (64, 16)

    gemm_xwT<1><<<gb, tb, 0, stream>>>(query, Wq, bq, qp, M_ROWS, E_SZ, E_SZ);
    gemm_xwT<1><<<gb, tb, 0, stream>>>(key,   Wk, bk, kp, M_ROWS, E_SZ, E_SZ);
    gemm_xwT<1><<<gb, tb, 0, stream>>>(value, Wv, bv, vp, M_ROWS, E_SZ, E_SZ);

    attn_fwd<<<dim3(S_LEN / 64, B_SZ * H_NUM), tb, 0, stream>>>(qp, kp, vp, ao);

    gemm_xwT<0><<<gb, tb, 0, stream>>>(ao, Wo, bo, out, M_ROWS, E_SZ, E_SZ);
}

// Round 2
// 640.454 us; speedup vs baseline: 2.1411x; 2.1411x over previous
//
#include <hip/hip_runtime.h>
#include <cstddef>

// Problem constants (S=2048, B=2, E=1024, H=16, D=64)
#define S_LEN 2048
#define B_SZ  2
#define E_SZ  1024
#define H_NUM 16
#define D_HEAD 64
#define M_ROWS 4096
#define NEG_BIG (-1e30f)

typedef __attribute__((ext_vector_type(8))) short bf16x8;
typedef __attribute__((ext_vector_type(4))) float f32x4;

// ---------------------------------------------------------------------------
// fp32 -> (hi, lo) bf16 split. hi = truncate-to-bf16(x) (exact top 8 mantissa
// bits), lo = RTNE-bf16(x - hi). A*B ~= Ah*Bh + Ah*Bl + Al*Bh captures all but
// the lo*lo term (~2^-16 rel) -> fp32-class accuracy on the matrix pipe.
// ---------------------------------------------------------------------------
__device__ __forceinline__ unsigned short rtne_bf16(float f) {
    unsigned int u = __float_as_uint(f);
    return (unsigned short)((u + 0x7fffu + ((u >> 16) & 1u)) >> 16);
}

__device__ __forceinline__ void split4(const float4 v, ushort4 &h, ushort4 &l) {
    const unsigned int ux = __float_as_uint(v.x);
    const unsigned int uy = __float_as_uint(v.y);
    const unsigned int uz = __float_as_uint(v.z);
    const unsigned int uw = __float_as_uint(v.w);
    h.x = (unsigned short)(ux >> 16);
    h.y = (unsigned short)(uy >> 16);
    h.z = (unsigned short)(uz >> 16);
    h.w = (unsigned short)(uw >> 16);
    l.x = rtne_bf16(v.x - __uint_as_float(ux & 0xffff0000u));
    l.y = rtne_bf16(v.y - __uint_as_float(uy & 0xffff0000u));
    l.z = rtne_bf16(v.z - __uint_as_float(uz & 0xffff0000u));
    l.w = rtne_bf16(v.w - __uint_as_float(uw & 0xffff0000u));
}

// ---------------------------------------------------------------------------
// Split-bf16 MFMA GEMM: C = A @ W^T + bias. A[M=4096,K=1024], W[N=1024,K=1024]
// both row-major (NT shape, both contiguous in K).
// Tile 128x128, BK=32, 4 waves in 2x2, each wave 64x64 = 4x4 frags of
// 16x16x32 MFMA. LDS layout k-group-major: [kg=k/8][row][8 bf16] so a lane's
// fragment read (row = base + (l&15), kg = l>>4) is a conflict-free
// ds_read_b128. 3 MFMAs per fragment pair (hi*hi, hi*lo, lo*hi).
// MODE 0: C row-major [M,1024] ; MODE 1: scatter to [B,H,S,D].
// ---------------------------------------------------------------------------
template <int MODE>
__device__ __forceinline__ void gemm_body(
    const float* __restrict__ A, const float* __restrict__ W,
    const float* __restrict__ bias, float* __restrict__ C)
{
    __shared__ unsigned short AhS[4096], AlS[4096], WhS[4096], WlS[4096];

    const int t  = threadIdx.x;
    const int m0 = blockIdx.x * 128;
    const int n0 = blockIdx.y * 128;

    // Staging map: tile is 128 rows x 32 k of fp32 = 1024 float4; thread t
    // owns float4 indices fi = t + i*256 (row = fi>>3, k4 = fi&7). 8 lanes
    // cover one 128B row segment -> coalesced.
    const float4* ag[4];
    const float4* wg[4];
    int sw[4];
#pragma unroll
    for (int i = 0; i < 4; ++i) {
        const int fi  = t + (i << 8);
        const int row = fi >> 3;
        const int k4  = fi & 7;
        ag[i] = (const float4*)(A + (size_t)(m0 + row) * 1024 + k4 * 4);
        wg[i] = (const float4*)(W + (size_t)(n0 + row) * 1024 + k4 * 4);
        // ushort index into [kg][row][8]: kg = k4>>1, half = k4&1
        sw[i] = ((k4 >> 1) << 10) + (row << 3) + ((k4 & 1) << 2);
    }

    const int lid = t & 63;
    const int wv  = t >> 6;
    const int wr  = wv >> 1, wc = wv & 1;
    const int kg  = lid >> 4, r16 = lid & 15;
    const int aB  = (kg << 10) + ((wr * 64 + r16) << 3);
    const int wB  = (kg << 10) + ((wc * 64 + r16) << 3);

    f32x4 acc[4][4];
    const f32x4 z = {0.f, 0.f, 0.f, 0.f};
#pragma unroll
    for (int m = 0; m < 4; ++m)
#pragma unroll
        for (int n = 0; n < 4; ++n) acc[m][n] = z;

    float4 pa[4], pw[4];
#pragma unroll
    for (int i = 0; i < 4; ++i) { pa[i] = ag[i][0]; pw[i] = wg[i][0]; }

    for (int kt = 0; kt < 1024; kt += 32) {
        __syncthreads();   // prior tile's readers done
#pragma unroll
        for (int i = 0; i < 4; ++i) {
            ushort4 h, l;
            split4(pa[i], h, l);
            *(ushort4*)&AhS[sw[i]] = h;
            *(ushort4*)&AlS[sw[i]] = l;
            split4(pw[i], h, l);
            *(ushort4*)&WhS[sw[i]] = h;
            *(ushort4*)&WlS[sw[i]] = l;
        }
        __syncthreads();   // tile ready
        if (kt + 32 < 1024) {        // issue next tile's global loads early;
            const int f = (kt >> 2) + 8;  // they fly under the MFMAs below
#pragma unroll
            for (int i = 0; i < 4; ++i) { pa[i] = ag[i][f]; pw[i] = wg[i][f]; }
        }

        bf16x8 ah[4], al[4], wh[4], wl[4];
#pragma unroll
        for (int m = 0; m < 4; ++m) {
            ah[m] = *(const bf16x8*)&AhS[aB + (m << 7)];
            al[m] = *(const bf16x8*)&AlS[aB + (m << 7)];
        }
#pragma unroll
        for (int n = 0; n < 4; ++n) {
            wh[n] = *(const bf16x8*)&WhS[wB + (n << 7)];
            wl[n] = *(const bf16x8*)&WlS[wB + (n << 7)];
        }
#pragma unroll
        for (int m = 0; m < 4; ++m)
#pragma unroll
            for (int n = 0; n < 4; ++n) {
                acc[m][n] = __builtin_amdgcn_mfma_f32_16x16x32_bf16(ah[m], wh[n], acc[m][n], 0, 0, 0);
                acc[m][n] = __builtin_amdgcn_mfma_f32_16x16x32_bf16(ah[m], wl[n], acc[m][n], 0, 0, 0);
                acc[m][n] = __builtin_amdgcn_mfma_f32_16x16x32_bf16(al[m], wh[n], acc[m][n], 0, 0, 0);
            }
    }

    // Epilogue. C/D frag map (verified m89/m91): col = lane&15,
    // row = (lane>>4)*4 + reg.
    float bn[4];
#pragma unroll
    for (int n = 0; n < 4; ++n) bn[n] = bias[n0 + wc * 64 + n * 16 + r16];

#pragma unroll
    for (int m = 0; m < 4; ++m) {
#pragma unroll
        for (int n = 0; n < 4; ++n) {
            const int col = n0 + wc * 64 + n * 16 + r16;
#pragma unroll
            for (int r = 0; r < 4; ++r) {
                const int row = m0 + wr * 64 + m * 16 + kg * 4 + r;
                const float val = acc[m][n][r] + bn[n];
                if (MODE == 0) {
                    C[(size_t)row * 1024 + col] = val;
                } else {
                    const int s = row >> 1, b = row & 1;
                    const int h = col >> 6, d = col & 63;
                    C[(((size_t)(b * H_NUM + h)) * S_LEN + s) * D_HEAD + d] = val;
                }
            }
        }
    }
}

__global__ __launch_bounds__(256, 2) void gemm_qkv(
    const float* __restrict__ q, const float* __restrict__ k, const float* __restrict__ v,
    const float* __restrict__ Wq, const float* __restrict__ Wk, const float* __restrict__ Wv,
    const float* __restrict__ bq, const float* __restrict__ bk, const float* __restrict__ bv,
    float* __restrict__ qp, float* __restrict__ kp, float* __restrict__ vp)
{
    const int z = blockIdx.z;
    const float* A = z == 0 ? q  : z == 1 ? k  : v;
    const float* W = z == 0 ? Wq : z == 1 ? Wk : Wv;
    const float* b = z == 0 ? bq : z == 1 ? bk : bv;
    float*       C = z == 0 ? qp : z == 1 ? kp : vp;
    gemm_body<1>(A, W, b, C);
}

__global__ __launch_bounds__(256, 2) void gemm_out(
    const float* __restrict__ A, const float* __restrict__ W,
    const float* __restrict__ bias, float* __restrict__ C)
{
    gemm_body<0>(A, W, bias, C);
}

// ---------------------------------------------------------------------------
// Causal flash attention, fp32 VALU (MFMA conversion next round).
// Load-balance fix: each block handles the q-tile PAIR (p, 31-p) -> exactly
// 33 k-tiles per block. Grid (16, 32) = 512 blocks = exactly 2/CU resident.
// ---------------------------------------------------------------------------
__global__ __launch_bounds__(256) void attn_fwd(
    const float* __restrict__ qp, const float* __restrict__ kp,
    const float* __restrict__ vp, float* __restrict__ outp)
{
    __shared__ float Qs[64][68];  // [d][qi]   (transposed)
    __shared__ float Ks[64][68];  // [d][ki]   (transposed)
    __shared__ float Vs[64][68];  // [ki][d]   (natural)
    __shared__ float Ps[64][68];  // [ki][qi]  (transposed P for PV)

    const int t  = threadIdx.x;
    const int tx = t & 15;
    const int ty = t >> 4;
    const int bh = blockIdx.y;       // b*H + h, 0..31

    const size_t base = (size_t)bh * S_LEN * D_HEAD;
    const float* qb = qp + base;
    const float* kb = kp + base;
    const float* vb = vp + base;

    const float scale = 0.125f;  // 1/sqrt(64)

    for (int pass = 0; pass < 2; ++pass) {
        const int qt = (pass == 0) ? blockIdx.x : 31 - blockIdx.x;
        const int q0 = qt * 64;

        __syncthreads();  // prior pass's Qs readers done before restage

        // Stage Q tile transposed: 1024 float4, 4 per thread. Coalesced.
#pragma unroll
        for (int l = 0; l < 4; ++l) {
            const int f   = t + l * 256;
            const int row = f >> 4;          // 0..63
            const int dp  = (f & 15) << 2;   // 0..60
            float4 v = *(const float4*)&qb[(size_t)(q0 + row) * D_HEAD + dp];
            Qs[dp + 0][row] = v.x; Qs[dp + 1][row] = v.y;
            Qs[dp + 2][row] = v.z; Qs[dp + 3][row] = v.w;
        }

        float m_r[4], l_r[4], o[4][4];
#pragma unroll
        for (int i = 0; i < 4; ++i) {
            m_r[i] = NEG_BIG; l_r[i] = 0.0f;
#pragma unroll
            for (int j = 0; j < 4; ++j) o[i][j] = 0.0f;
        }

        for (int ktile = 0; ktile <= qt; ++ktile) {
            const int k0 = ktile * 64;
            __syncthreads();  // protect Ks/Vs/Ps from prior readers (and Qs ready)

#pragma unroll
            for (int l = 0; l < 4; ++l) {
                const int f   = t + l * 256;
                const int row = f >> 4;
                const int dp  = (f & 15) << 2;
                float4 kv = *(const float4*)&kb[(size_t)(k0 + row) * D_HEAD + dp];
                Ks[dp + 0][row] = kv.x; Ks[dp + 1][row] = kv.y;
                Ks[dp + 2][row] = kv.z; Ks[dp + 3][row] = kv.w;
                float4 vv = *(const float4*)&vb[(size_t)(k0 + row) * D_HEAD + dp];
                *(float4*)&Vs[row][dp] = vv;
            }
            __syncthreads();

            // ---- scores ----
            float s[4][4] = {};
#pragma unroll
            for (int d = 0; d < 64; ++d) {
                const float4 q4 = *(const float4*)&Qs[d][ty * 4];
                const float4 k4 = *(const float4*)&Ks[d][tx * 4];
                const float qa[4] = {q4.x, q4.y, q4.z, q4.w};
                const float ka[4] = {k4.x, k4.y, k4.z, k4.w};
#pragma unroll
                for (int i = 0; i < 4; ++i)
#pragma unroll
                    for (int j = 0; j < 4; ++j)
                        s[i][j] = fmaf(qa[i], ka[j], s[i][j]);
            }

            // ---- scale + causal mask + row max ----
            float rm[4];
#pragma unroll
            for (int i = 0; i < 4; ++i) {
                rm[i] = NEG_BIG;
                const int qg = q0 + ty * 4 + i;
#pragma unroll
                for (int j = 0; j < 4; ++j) {
                    const int kg2 = k0 + tx * 4 + j;
                    s[i][j] *= scale;
                    if (kg2 > qg) s[i][j] = NEG_BIG;
                    rm[i] = fmaxf(rm[i], s[i][j]);
                }
            }
#pragma unroll
            for (int off = 1; off < 16; off <<= 1)
#pragma unroll
                for (int i = 0; i < 4; ++i)
                    rm[i] = fmaxf(rm[i], __shfl_xor(rm[i], off, 64));

            float mn[4], sc[4];
#pragma unroll
            for (int i = 0; i < 4; ++i) {
                mn[i] = fmaxf(m_r[i], rm[i]);
                sc[i] = __expf(m_r[i] - mn[i]);
                m_r[i] = mn[i];
            }

            // ---- p = exp(s - m), zeroed where masked ----
            float rs[4] = {0.f, 0.f, 0.f, 0.f};
#pragma unroll
            for (int i = 0; i < 4; ++i) {
                const int qg = q0 + ty * 4 + i;
#pragma unroll
                for (int j = 0; j < 4; ++j) {
                    const int kg2 = k0 + tx * 4 + j;
                    const float p = (kg2 > qg) ? 0.0f : __expf(s[i][j] - mn[i]);
                    s[i][j] = p;
                    rs[i] += p;
                }
            }
#pragma unroll
            for (int off = 1; off < 16; off <<= 1)
#pragma unroll
                for (int i = 0; i < 4; ++i)
                    rs[i] += __shfl_xor(rs[i], off, 64);

#pragma unroll
            for (int i = 0; i < 4; ++i) {
                l_r[i] = l_r[i] * sc[i] + rs[i];
#pragma unroll
                for (int j = 0; j < 4; ++j) o[i][j] *= sc[i];
            }

            // ---- stage P transposed for PV ----
#pragma unroll
            for (int i = 0; i < 4; ++i)
#pragma unroll
                for (int j = 0; j < 4; ++j)
                    Ps[tx * 4 + j][ty * 4 + i] = s[i][j];
            __syncthreads();

            // ---- O += P^T @ V ----
#pragma unroll
            for (int kk = 0; kk < 64; ++kk) {
                const float4 p4 = *(const float4*)&Ps[kk][ty * 4];
                const float4 v4 = *(const float4*)&Vs[kk][tx * 4];
                const float pa2[4] = {p4.x, p4.y, p4.z, p4.w};
                const float va[4] = {v4.x, v4.y, v4.z, v4.w};
#pragma unroll
                for (int i = 0; i < 4; ++i)
#pragma unroll
                    for (int j = 0; j < 4; ++j)
                        o[i][j] = fmaf(pa2[i], va[j], o[i][j]);
            }
        }

        // ---- epilogue: divide by row sum, write [S,B,E] ----
        const int b = bh / H_NUM;
        const int h = bh % H_NUM;
#pragma unroll
        for (int i = 0; i < 4; ++i) {
            const int sg = q0 + ty * 4 + i;
            const float inv = 1.0f / l_r[i];
            float4 ov;
            ov.x = o[i][0] * inv; ov.y = o[i][1] * inv;
            ov.z = o[i][2] * inv; ov.w = o[i][3] * inv;
            *(float4*)&outp[((size_t)sg * B_SZ + b) * E_SZ + h * D_HEAD + tx * 4] = ov;
        }
    }
}

// ---------------------------------------------------------------------------
extern "C" void kernel_launch(void* const* d_in, const int* in_sizes, int n_in,
                              void* d_out, int out_size, void* d_ws, size_t ws_size,
                              hipStream_t stream)
{
    const float* query = (const float*)d_in[0];
    const float* key   = (const float*)d_in[1];
    const float* value = (const float*)d_in[2];
    const float* Wq = (const float*)d_in[3];  const float* bq = (const float*)d_in[4];
    const float* Wk = (const float*)d_in[5];  const float* bk = (const float*)d_in[6];
    const float* Wv = (const float*)d_in[7];  const float* bv = (const float*)d_in[8];
    const float* Wo = (const float*)d_in[9];  const float* bo = (const float*)d_in[10];
    float* out = (float*)d_out;

    // Workspace: qp,kp,vp in [B,H,S,D]; ao in [S,B,E]. 16M floats = 64 MB.
    const size_t PLANE = (size_t)M_ROWS * E_SZ;
    float* ws = (float*)d_ws;
    float* qp = ws;
    float* kp = qp + PLANE;
    float* vp = kp + PLANE;
    float* ao = vp + PLANE;
    (void)ws_size; (void)in_sizes; (void)n_in; (void)out_size;

    const dim3 tb(256);

    gemm_qkv<<<dim3(32, 8, 3), tb, 0, stream>>>(query, key, value,
                                                Wq, Wk, Wv, bq, bk, bv,
                                                qp, kp, vp);

    attn_fwd<<<dim3(16, 32), tb, 0, stream>>>(qp, kp, vp, ao);

    gemm_out<<<dim3(32, 8), tb, 0, stream>>>(ao, Wo, bo, out);
}

// Round 3
// 419.213 us; speedup vs baseline: 3.2711x; 1.5278x over previous
//
#include <hip/hip_runtime.h>
#include <cstddef>

// Problem constants (S=2048, B=2, E=1024, H=16, D=64)
#define S_LEN 2048
#define B_SZ  2
#define E_SZ  1024
#define H_NUM 16
#define D_HEAD 64
#define M_ROWS 4096
#define NEG_BIG (-1e30f)

typedef __attribute__((ext_vector_type(8))) short bf16x8;
typedef __attribute__((ext_vector_type(4))) float f32x4;

// ---------------------------------------------------------------------------
// fp32 -> (hi, lo) bf16 split. hi = truncate-to-bf16(x), lo = RTNE-bf16(x-hi).
// A*B ~= Ah*Bh + Ah*Bl + Al*Bh -> fp32-class accuracy on the matrix pipe.
// ---------------------------------------------------------------------------
__device__ __forceinline__ unsigned short rtne_bf16(float f) {
    unsigned int u = __float_as_uint(f);
    return (unsigned short)((u + 0x7fffu + ((u >> 16) & 1u)) >> 16);
}

__device__ __forceinline__ void split1(float f, unsigned short &h, unsigned short &l) {
    const unsigned int u = __float_as_uint(f);
    h = (unsigned short)(u >> 16);
    l = rtne_bf16(f - __uint_as_float(u & 0xffff0000u));
}

__device__ __forceinline__ void split4(const float4 v, ushort4 &h, ushort4 &l) {
    const unsigned int ux = __float_as_uint(v.x);
    const unsigned int uy = __float_as_uint(v.y);
    const unsigned int uz = __float_as_uint(v.z);
    const unsigned int uw = __float_as_uint(v.w);
    h.x = (unsigned short)(ux >> 16);
    h.y = (unsigned short)(uy >> 16);
    h.z = (unsigned short)(uz >> 16);
    h.w = (unsigned short)(uw >> 16);
    l.x = rtne_bf16(v.x - __uint_as_float(ux & 0xffff0000u));
    l.y = rtne_bf16(v.y - __uint_as_float(uy & 0xffff0000u));
    l.z = rtne_bf16(v.z - __uint_as_float(uz & 0xffff0000u));
    l.w = rtne_bf16(v.w - __uint_as_float(uw & 0xffff0000u));
}

// ---------------------------------------------------------------------------
// Split-bf16 MFMA GEMM (unchanged from round 2): C = A @ W^T + bias.
// ---------------------------------------------------------------------------
template <int MODE>
__device__ __forceinline__ void gemm_body(
    const float* __restrict__ A, const float* __restrict__ W,
    const float* __restrict__ bias, float* __restrict__ C)
{
    __shared__ unsigned short AhS[4096], AlS[4096], WhS[4096], WlS[4096];

    const int t  = threadIdx.x;
    const int m0 = blockIdx.x * 128;
    const int n0 = blockIdx.y * 128;

    const float4* ag[4];
    const float4* wg[4];
    int sw[4];
#pragma unroll
    for (int i = 0; i < 4; ++i) {
        const int fi  = t + (i << 8);
        const int row = fi >> 3;
        const int k4  = fi & 7;
        ag[i] = (const float4*)(A + (size_t)(m0 + row) * 1024 + k4 * 4);
        wg[i] = (const float4*)(W + (size_t)(n0 + row) * 1024 + k4 * 4);
        sw[i] = ((k4 >> 1) << 10) + (row << 3) + ((k4 & 1) << 2);
    }

    const int lid = t & 63;
    const int wv  = t >> 6;
    const int wr  = wv >> 1, wc = wv & 1;
    const int kg  = lid >> 4, r16 = lid & 15;
    const int aB  = (kg << 10) + ((wr * 64 + r16) << 3);
    const int wB  = (kg << 10) + ((wc * 64 + r16) << 3);

    f32x4 acc[4][4];
    const f32x4 z = {0.f, 0.f, 0.f, 0.f};
#pragma unroll
    for (int m = 0; m < 4; ++m)
#pragma unroll
        for (int n = 0; n < 4; ++n) acc[m][n] = z;

    float4 pa[4], pw[4];
#pragma unroll
    for (int i = 0; i < 4; ++i) { pa[i] = ag[i][0]; pw[i] = wg[i][0]; }

    for (int kt = 0; kt < 1024; kt += 32) {
        __syncthreads();
#pragma unroll
        for (int i = 0; i < 4; ++i) {
            ushort4 h, l;
            split4(pa[i], h, l);
            *(ushort4*)&AhS[sw[i]] = h;
            *(ushort4*)&AlS[sw[i]] = l;
            split4(pw[i], h, l);
            *(ushort4*)&WhS[sw[i]] = h;
            *(ushort4*)&WlS[sw[i]] = l;
        }
        __syncthreads();
        if (kt + 32 < 1024) {
            const int f = (kt >> 2) + 8;
#pragma unroll
            for (int i = 0; i < 4; ++i) { pa[i] = ag[i][f]; pw[i] = wg[i][f]; }
        }

        bf16x8 ah[4], al[4], wh[4], wl[4];
#pragma unroll
        for (int m = 0; m < 4; ++m) {
            ah[m] = *(const bf16x8*)&AhS[aB + (m << 7)];
            al[m] = *(const bf16x8*)&AlS[aB + (m << 7)];
        }
#pragma unroll
        for (int n = 0; n < 4; ++n) {
            wh[n] = *(const bf16x8*)&WhS[wB + (n << 7)];
            wl[n] = *(const bf16x8*)&WlS[wB + (n << 7)];
        }
#pragma unroll
        for (int m = 0; m < 4; ++m)
#pragma unroll
            for (int n = 0; n < 4; ++n) {
                acc[m][n] = __builtin_amdgcn_mfma_f32_16x16x32_bf16(ah[m], wh[n], acc[m][n], 0, 0, 0);
                acc[m][n] = __builtin_amdgcn_mfma_f32_16x16x32_bf16(ah[m], wl[n], acc[m][n], 0, 0, 0);
                acc[m][n] = __builtin_amdgcn_mfma_f32_16x16x32_bf16(al[m], wh[n], acc[m][n], 0, 0, 0);
            }
    }

    float bn[4];
#pragma unroll
    for (int n = 0; n < 4; ++n) bn[n] = bias[n0 + wc * 64 + n * 16 + r16];

#pragma unroll
    for (int m = 0; m < 4; ++m) {
#pragma unroll
        for (int n = 0; n < 4; ++n) {
            const int col = n0 + wc * 64 + n * 16 + r16;
#pragma unroll
            for (int r = 0; r < 4; ++r) {
                const int row = m0 + wr * 64 + m * 16 + kg * 4 + r;
                const float val = acc[m][n][r] + bn[n];
                if (MODE == 0) {
                    C[(size_t)row * 1024 + col] = val;
                } else {
                    const int s = row >> 1, b = row & 1;
                    const int h = col >> 6, d = col & 63;
                    C[(((size_t)(b * H_NUM + h)) * S_LEN + s) * D_HEAD + d] = val;
                }
            }
        }
    }
}

__global__ __launch_bounds__(256, 2) void gemm_qkv(
    const float* __restrict__ q, const float* __restrict__ k, const float* __restrict__ v,
    const float* __restrict__ Wq, const float* __restrict__ Wk, const float* __restrict__ Wv,
    const float* __restrict__ bq, const float* __restrict__ bk, const float* __restrict__ bv,
    float* __restrict__ qp, float* __restrict__ kp, float* __restrict__ vp)
{
    const int z = blockIdx.z;
    const float* A = z == 0 ? q  : z == 1 ? k  : v;
    const float* W = z == 0 ? Wq : z == 1 ? Wk : Wv;
    const float* b = z == 0 ? bq : z == 1 ? bk : bv;
    float*       C = z == 0 ? qp : z == 1 ? kp : vp;
    gemm_body<1>(A, W, b, C);
}

__global__ __launch_bounds__(256, 2) void gemm_out(
    const float* __restrict__ A, const float* __restrict__ W,
    const float* __restrict__ bias, float* __restrict__ C)
{
    gemm_body<0>(A, W, bias, C);
}

// ---------------------------------------------------------------------------
// Causal flash attention via split-bf16 MFMA.
// Block = 256 threads = 4 waves; each block does q-tile pair (p, 31-p) for one
// bh -> exactly 33 k-tiles. Each wave owns 16 q-rows.
// LDS tiles [64][64] bf16 with XOR-16B-slot swizzle -> conflict-free
// ds_read_b128 fragments. Q-buffer aliased with P-buffer: 48 KB -> 3 blk/CU.
// QK^T: a=Qfrag[q][d], b=Kfrag[k][d] -> S C-layout row=q=(g*4+reg),
// col=k=r16 (+16*nf). PV: a=Pfrag[q][k], b=VTfrag[d][k] -> O same row map.
// ---------------------------------------------------------------------------
__device__ __forceinline__ int swz(int row, int col) {
    // ushort index into a [64][64] tile, 16B slots XOR'd by row&7
    return (row << 6) + ((((col >> 3) ^ (row & 7)) << 3)) + (col & 7);
}

__global__ __launch_bounds__(256, 3) void attn_fwd(
    const float* __restrict__ qp, const float* __restrict__ kp,
    const float* __restrict__ vp, float* __restrict__ outp)
{
    __shared__ unsigned short smm[6 * 4096];   // 48 KB
    unsigned short* KH  = smm;
    unsigned short* KL  = smm + 4096;
    unsigned short* VTH = smm + 8192;    // [d][k]
    unsigned short* VTL = smm + 12288;
    unsigned short* PQH = smm + 16384;   // Q at pass start, then P  [q][k]
    unsigned short* PQL = smm + 20480;

    const int t   = threadIdx.x;
    const int lid = t & 63;
    const int w   = t >> 6;        // wave 0..3 -> q rows w*16..w*16+15
    const int g   = lid >> 4;      // k-group
    const int r16 = lid & 15;
    const int bh  = blockIdx.y;

    const size_t base = (size_t)bh * S_LEN * D_HEAD;
    const float* qb = qp + base;
    const float* kb = kp + base;
    const float* vb = vp + base;

    // staging map: 64 rows x 16 float4; thread t handles fi = t + i*256
    int srow[4], scol[4];
#pragma unroll
    for (int i = 0; i < 4; ++i) {
        const int fi = t + (i << 8);
        srow[i] = fi >> 4;
        scol[i] = (fi & 15) << 2;
    }
    const int jrot = (t >> 2) & 3;   // rotate V-transpose write order (banks)

    const float scale = 0.125f;  // 1/sqrt(64)

    for (int pass = 0; pass < 2; ++pass) {
        const int qt = (pass == 0) ? blockIdx.x : 31 - blockIdx.x;
        const int q0 = qt * 64;

        __syncthreads();  // prior pass's P readers done before Q restage

        // ---- stage Q (hi/lo) into PQ buffers ----
#pragma unroll
        for (int i = 0; i < 4; ++i) {
            float4 qv = *(const float4*)&qb[(size_t)(q0 + srow[i]) * D_HEAD + scol[i]];
            ushort4 h, l;
            split4(qv, h, l);
            *(ushort4*)&PQH[swz(srow[i], scol[i])] = h;
            *(ushort4*)&PQL[swz(srow[i], scol[i])] = l;
        }
        __syncthreads();

        // ---- Q fragments to registers (A-operand rows w*16+r16) ----
        bf16x8 qh[2], ql[2];
#pragma unroll
        for (int ks = 0; ks < 2; ++ks) {
            const int off = swz(w * 16 + r16, ks * 32 + g * 8);
            qh[ks] = *(const bf16x8*)&PQH[off];
            ql[ks] = *(const bf16x8*)&PQL[off];
        }

        f32x4 oacc[4];
        const f32x4 z = {0.f, 0.f, 0.f, 0.f};
        float m_r[4], l_r[4];
#pragma unroll
        for (int i = 0; i < 4; ++i) { oacc[i] = z; m_r[i] = NEG_BIG; l_r[i] = 0.f; }

        for (int ktile = 0; ktile <= qt; ++ktile) {
            const int k0 = ktile * 64;
            __syncthreads();  // prior iter's K/VT readers done (and Q reads on iter 0)

            // ---- stage K [k][d] and V transposed [d][k] ----
#pragma unroll
            for (int i = 0; i < 4; ++i) {
                float4 kv = *(const float4*)&kb[(size_t)(k0 + srow[i]) * D_HEAD + scol[i]];
                ushort4 h, l;
                split4(kv, h, l);
                *(ushort4*)&KH[swz(srow[i], scol[i])] = h;
                *(ushort4*)&KL[swz(srow[i], scol[i])] = l;

                float4 vv = *(const float4*)&vb[(size_t)(k0 + srow[i]) * D_HEAD + scol[i]];
                const float vals[4] = {vv.x, vv.y, vv.z, vv.w};
#pragma unroll
                for (int jj = 0; jj < 4; ++jj) {
                    const int j = (jj + jrot) & 3;     // spread banks across lanes
                    unsigned short h1, l1;
                    split1(vals[j], h1, l1);
                    const int o = swz(scol[i] + j, srow[i]);
                    VTH[o] = h1;
                    VTL[o] = l1;
                }
            }
            __syncthreads();

            // ---- scores: S[q][k] (3-pass split) ----
            f32x4 sacc[4];
#pragma unroll
            for (int nf = 0; nf < 4; ++nf) sacc[nf] = z;
#pragma unroll
            for (int nf = 0; nf < 4; ++nf) {
#pragma unroll
                for (int ks = 0; ks < 2; ++ks) {
                    const int off = swz(nf * 16 + r16, ks * 32 + g * 8);
                    bf16x8 kh = *(const bf16x8*)&KH[off];
                    bf16x8 kl = *(const bf16x8*)&KL[off];
                    sacc[nf] = __builtin_amdgcn_mfma_f32_16x16x32_bf16(qh[ks], kh, sacc[nf], 0, 0, 0);
                    sacc[nf] = __builtin_amdgcn_mfma_f32_16x16x32_bf16(qh[ks], kl, sacc[nf], 0, 0, 0);
                    sacc[nf] = __builtin_amdgcn_mfma_f32_16x16x32_bf16(ql[ks], kh, sacc[nf], 0, 0, 0);
                }
            }

            // ---- softmax (fp32, per-lane rows q = q0 + w*16 + g*4 + r) ----
            float rm[4] = {NEG_BIG, NEG_BIG, NEG_BIG, NEG_BIG};
#pragma unroll
            for (int nf = 0; nf < 4; ++nf) {
                const int k_abs = k0 + nf * 16 + r16;
#pragma unroll
                for (int r = 0; r < 4; ++r) {
                    const int q_abs = q0 + w * 16 + g * 4 + r;
                    float val = sacc[nf][r] * scale;
                    if (k_abs > q_abs) val = NEG_BIG;
                    sacc[nf][r] = val;
                    rm[r] = fmaxf(rm[r], val);
                }
            }
#pragma unroll
            for (int off = 1; off < 16; off <<= 1)
#pragma unroll
                for (int r = 0; r < 4; ++r)
                    rm[r] = fmaxf(rm[r], __shfl_xor(rm[r], off, 64));

            float scf[4];
#pragma unroll
            for (int r = 0; r < 4; ++r) {
                const float mn = fmaxf(m_r[r], rm[r]);
                scf[r] = __expf(m_r[r] - mn);
                m_r[r] = mn;
            }

            float pv4[4][4];
            float rs[4] = {0.f, 0.f, 0.f, 0.f};
#pragma unroll
            for (int nf = 0; nf < 4; ++nf)
#pragma unroll
                for (int r = 0; r < 4; ++r) {
                    const float p = __expf(sacc[nf][r] - m_r[r]);  // masked -> exp(-huge) = 0
                    pv4[nf][r] = p;
                    rs[r] += p;
                }
#pragma unroll
            for (int off = 1; off < 16; off <<= 1)
#pragma unroll
                for (int r = 0; r < 4; ++r)
                    rs[r] += __shfl_xor(rs[r], off, 64);

#pragma unroll
            for (int r = 0; r < 4; ++r) {
                l_r[r] = l_r[r] * scf[r] + rs[r];
#pragma unroll
                for (int nf = 0; nf < 4; ++nf) oacc[nf][r] *= scf[r];
            }

            // ---- write P (hi/lo) to own wave's rows of PQ ----
#pragma unroll
            for (int nf = 0; nf < 4; ++nf)
#pragma unroll
                for (int r = 0; r < 4; ++r) {
                    unsigned short h1, l1;
                    split1(pv4[nf][r], h1, l1);
                    const int o = swz(w * 16 + g * 4 + r, nf * 16 + r16);
                    PQH[o] = h1;
                    PQL[o] = l1;
                }
            // Same-wave LDS visibility only (reads below hit own wave's rows);
            // compiler orders via lgkmcnt — no barrier needed.

            // ---- O += P @ V (3-pass split) ----
#pragma unroll
            for (int ks = 0; ks < 2; ++ks) {
                const int poff = swz(w * 16 + r16, ks * 32 + g * 8);
                bf16x8 pah = *(const bf16x8*)&PQH[poff];
                bf16x8 pal = *(const bf16x8*)&PQL[poff];
#pragma unroll
                for (int nf = 0; nf < 4; ++nf) {
                    const int voff = swz(nf * 16 + r16, ks * 32 + g * 8);
                    bf16x8 vh = *(const bf16x8*)&VTH[voff];
                    bf16x8 vl = *(const bf16x8*)&VTL[voff];
                    oacc[nf] = __builtin_amdgcn_mfma_f32_16x16x32_bf16(pah, vh, oacc[nf], 0, 0, 0);
                    oacc[nf] = __builtin_amdgcn_mfma_f32_16x16x32_bf16(pah, vl, oacc[nf], 0, 0, 0);
                    oacc[nf] = __builtin_amdgcn_mfma_f32_16x16x32_bf16(pal, vh, oacc[nf], 0, 0, 0);
                }
            }
        }

        // ---- epilogue: O / l -> [S,B,E] ----
        const int b = bh / H_NUM;
        const int h = bh % H_NUM;
        float inv[4];
#pragma unroll
        for (int r = 0; r < 4; ++r) inv[r] = 1.0f / l_r[r];
#pragma unroll
        for (int nf = 0; nf < 4; ++nf) {
            const int d = nf * 16 + r16;
#pragma unroll
            for (int r = 0; r < 4; ++r) {
                const int s = q0 + w * 16 + g * 4 + r;
                outp[((size_t)s * B_SZ + b) * E_SZ + h * D_HEAD + d] = oacc[nf][r] * inv[r];
            }
        }
    }
}

// ---------------------------------------------------------------------------
extern "C" void kernel_launch(void* const* d_in, const int* in_sizes, int n_in,
                              void* d_out, int out_size, void* d_ws, size_t ws_size,
                              hipStream_t stream)
{
    const float* query = (const float*)d_in[0];
    const float* key   = (const float*)d_in[1];
    const float* value = (const float*)d_in[2];
    const float* Wq = (const float*)d_in[3];  const float* bq = (const float*)d_in[4];
    const float* Wk = (const float*)d_in[5];  const float* bk = (const float*)d_in[6];
    const float* Wv = (const float*)d_in[7];  const float* bv = (const float*)d_in[8];
    const float* Wo = (const float*)d_in[9];  const float* bo = (const float*)d_in[10];
    float* out = (float*)d_out;

    const size_t PLANE = (size_t)M_ROWS * E_SZ;
    float* ws = (float*)d_ws;
    float* qp = ws;
    float* kp = qp + PLANE;
    float* vp = kp + PLANE;
    float* ao = vp + PLANE;
    (void)ws_size; (void)in_sizes; (void)n_in; (void)out_size;

    const dim3 tb(256);

    gemm_qkv<<<dim3(32, 8, 3), tb, 0, stream>>>(query, key, value,
                                                Wq, Wk, Wv, bq, bk, bv,
                                                qp, kp, vp);

    attn_fwd<<<dim3(16, 32), tb, 0, stream>>>(qp, kp, vp, ao);

    gemm_out<<<dim3(32, 8), tb, 0, stream>>>(ao, Wo, bo, out);
}

// Round 4
// 344.171 us; speedup vs baseline: 3.9843x; 1.2180x over previous
//
#include <hip/hip_runtime.h>
#include <cstddef>
#include <cstdint>

// Problem constants (S=2048, B=2, E=1024, H=16, D=64)
#define S_LEN 2048
#define B_SZ  2
#define E_SZ  1024
#define H_NUM 16
#define D_HEAD 64
#define M_ROWS 4096
#define NEG_BIG (-1e30f)

typedef __attribute__((ext_vector_type(8))) short bf16x8;
typedef __attribute__((ext_vector_type(4))) float f32x4;

// ---------------------------------------------------------------------------
// Workspace layout (byte offsets). Peak footprint 112 MB.
// Input planes (dead after QKV GEMM) are reused for the attention output.
// ---------------------------------------------------------------------------
#define P_QRYH (0ull << 20)
#define P_QRYL (8ull << 20)
#define P_KEYH (16ull << 20)
#define P_KEYL (24ull << 20)
#define P_VALH (32ull << 20)
#define P_VALL (40ull << 20)
#define P_WQH  (48ull << 20)
#define P_WQL  (50ull << 20)
#define P_WKH  (52ull << 20)
#define P_WKL  (54ull << 20)
#define P_WVH  (56ull << 20)
#define P_WVL  (58ull << 20)
#define P_WOH  (60ull << 20)
#define P_WOL  (62ull << 20)
#define P_QPH  (64ull << 20)   // Q proj planes [B,H,S,D]
#define P_QPL  (72ull << 20)
#define P_KPH  (80ull << 20)
#define P_KPL  (88ull << 20)
#define P_VTH  (96ull << 20)   // V proj planes TRANSPOSED [B,H,D,S]
#define P_VTL  (104ull << 20)
#define P_AOH  (0ull << 20)    // attn out planes [S,B,E] (alias query planes)
#define P_AOL  (8ull << 20)

// ---------------------------------------------------------------------------
// fp32 -> (hi, lo) bf16 split. hi = truncate-to-bf16(x), lo = RTNE-bf16(x-hi).
// A*B ~= Ah*Bh + Ah*Bl + Al*Bh -> fp32-class accuracy on the matrix pipe.
// ---------------------------------------------------------------------------
__device__ __forceinline__ unsigned short rtne_bf16(float f) {
    unsigned int u = __float_as_uint(f);
    return (unsigned short)((u + 0x7fffu + ((u >> 16) & 1u)) >> 16);
}

__device__ __forceinline__ void split1(float f, unsigned short &h, unsigned short &l) {
    const unsigned int u = __float_as_uint(f);
    h = (unsigned short)(u >> 16);
    l = rtne_bf16(f - __uint_as_float(u & 0xffff0000u));
}

__device__ __forceinline__ void split4(const float4 v, ushort4 &h, ushort4 &l) {
    const unsigned int ux = __float_as_uint(v.x);
    const unsigned int uy = __float_as_uint(v.y);
    const unsigned int uz = __float_as_uint(v.z);
    const unsigned int uw = __float_as_uint(v.w);
    h.x = (unsigned short)(ux >> 16);
    h.y = (unsigned short)(uy >> 16);
    h.z = (unsigned short)(uz >> 16);
    h.w = (unsigned short)(uw >> 16);
    l.x = rtne_bf16(v.x - __uint_as_float(ux & 0xffff0000u));
    l.y = rtne_bf16(v.y - __uint_as_float(uy & 0xffff0000u));
    l.z = rtne_bf16(v.z - __uint_as_float(uz & 0xffff0000u));
    l.w = rtne_bf16(v.w - __uint_as_float(uw & 0xffff0000u));
}

// Async global->LDS, 16B per lane. LDS dest = wave-uniform base + lane*16.
__device__ __forceinline__ void gl16(const void* g, void* l) {
    __builtin_amdgcn_global_load_lds(
        (const __attribute__((address_space(1))) void*)g,
        (__attribute__((address_space(3))) void*)l, 16, 0, 0);
}

// ---------------------------------------------------------------------------
// Pre-split: all GEMM inputs -> hi/lo bf16 planes. grid (4096, 7).
// ---------------------------------------------------------------------------
__global__ __launch_bounds__(256) void split_planes(
    const float* __restrict__ q, const float* __restrict__ k, const float* __restrict__ v,
    const float* __restrict__ wq, const float* __restrict__ wk,
    const float* __restrict__ wv, const float* __restrict__ wo,
    unsigned char* __restrict__ ws)
{
    const int z = blockIdx.y;
    const float* src; size_t oh, ol; int n;
    switch (z) {
        case 0: src = q;  oh = P_QRYH; ol = P_QRYL; n = 4194304; break;
        case 1: src = k;  oh = P_KEYH; ol = P_KEYL; n = 4194304; break;
        case 2: src = v;  oh = P_VALH; ol = P_VALL; n = 4194304; break;
        case 3: src = wq; oh = P_WQH;  ol = P_WQL;  n = 1048576; break;
        case 4: src = wk; oh = P_WKH;  ol = P_WKL;  n = 1048576; break;
        case 5: src = wv; oh = P_WVH;  ol = P_WVL;  n = 1048576; break;
        default:src = wo; oh = P_WOH;  ol = P_WOL;  n = 1048576; break;
    }
    const int i = blockIdx.x * 256 + threadIdx.x;  // float4 index
    if (i * 4 >= n) return;
    float4 vv = *(const float4*)&src[(size_t)i * 4];
    ushort4 h, l;
    split4(vv, h, l);
    *(ushort4*)(ws + oh + (size_t)i * 8) = h;
    *(ushort4*)(ws + ol + (size_t)i * 8) = l;
}

// ---------------------------------------------------------------------------
// QKV GEMM from planes: C = A @ W^T + bias, M=4096, N=K=1024.
// 128x128 tile, BK=32, 4 waves 2x2, 3-pass split MFMA, gload_lds staging with
// pre-swizzled source (XOR 16B slot by row&3 inside 64B rows).
// z=0 -> Q planes [B,H,S,D]; z=1 -> K planes; z=2 -> V planes transposed.
// ---------------------------------------------------------------------------
__global__ __launch_bounds__(256, 3) void gemm_qkv_planes(
    const float* __restrict__ bq, const float* __restrict__ bk, const float* __restrict__ bv,
    unsigned char* __restrict__ ws)
{
    __shared__ unsigned short AH[4096], AL[4096], WH[4096], WL[4096];  // 128x32 each

    const int z = blockIdx.z;
    const unsigned char* aph = ws + (z == 0 ? P_QRYH : z == 1 ? P_KEYH : P_VALH);
    const unsigned char* apl = ws + (z == 0 ? P_QRYL : z == 1 ? P_KEYL : P_VALL);
    const unsigned char* wph = ws + (z == 0 ? P_WQH : z == 1 ? P_WKH : P_WVH);
    const unsigned char* wpl = ws + (z == 0 ? P_WQL : z == 1 ? P_WKL : P_WVL);
    const float* bias = z == 0 ? bq : z == 1 ? bk : bv;

    const int t = threadIdx.x, lid = t & 63, w = t >> 6;
    const int wr = w >> 1, wc = w & 1, g = lid >> 4, r16 = lid & 15;
    const int m0 = blockIdx.x * 128, n0 = blockIdx.y * 128;

    const int lrow = lid >> 2;                 // 0..15 (row within 1KB issue)
    const int cA = (lid & 3) ^ (lrow & 3);     // swizzled source k-chunk

    int offA[4], offW[4];
#pragma unroll
    for (int m = 0; m < 4; ++m)
        offA[m] = (wr * 64 + m * 16 + r16) * 32 + ((g ^ (r16 & 3)) << 3);
#pragma unroll
    for (int n = 0; n < 4; ++n)
        offW[n] = (wc * 64 + n * 16 + r16) * 32 + ((g ^ (r16 & 3)) << 3);

    f32x4 acc[4][4];
    const f32x4 zero = {0.f, 0.f, 0.f, 0.f};
#pragma unroll
    for (int m = 0; m < 4; ++m)
#pragma unroll
        for (int n = 0; n < 4; ++n) acc[m][n] = zero;

    for (int kt = 0; kt < 1024; kt += 32) {
        __syncthreads();   // prior tile's readers done
#pragma unroll
        for (int i = 0; i < 2; ++i) {
            const int ra = m0 + w * 32 + i * 16 + lrow;
            const size_t ab = (size_t)ra * 2048 + (size_t)kt * 2 + (size_t)cA * 16;
            gl16(aph + ab, &AH[(w * 32 + i * 16) * 32]);
            gl16(apl + ab, &AL[(w * 32 + i * 16) * 32]);
            const int rw = n0 + w * 32 + i * 16 + lrow;
            const size_t wb = (size_t)rw * 2048 + (size_t)kt * 2 + (size_t)cA * 16;
            gl16(wph + wb, &WH[(w * 32 + i * 16) * 32]);
            gl16(wpl + wb, &WL[(w * 32 + i * 16) * 32]);
        }
        __syncthreads();   // vmcnt(0) drained by compiler before barrier

        bf16x8 ah[4], al[4], whf[4], wlf[4];
#pragma unroll
        for (int m = 0; m < 4; ++m) {
            ah[m] = *(const bf16x8*)&AH[offA[m]];
            al[m] = *(const bf16x8*)&AL[offA[m]];
        }
#pragma unroll
        for (int n = 0; n < 4; ++n) {
            whf[n] = *(const bf16x8*)&WH[offW[n]];
            wlf[n] = *(const bf16x8*)&WL[offW[n]];
        }
#pragma unroll
        for (int m = 0; m < 4; ++m)
#pragma unroll
            for (int n = 0; n < 4; ++n) {
                acc[m][n] = __builtin_amdgcn_mfma_f32_16x16x32_bf16(ah[m], whf[n], acc[m][n], 0, 0, 0);
                acc[m][n] = __builtin_amdgcn_mfma_f32_16x16x32_bf16(ah[m], wlf[n], acc[m][n], 0, 0, 0);
                acc[m][n] = __builtin_amdgcn_mfma_f32_16x16x32_bf16(al[m], whf[n], acc[m][n], 0, 0, 0);
            }
    }

    // Epilogue: add bias, split to planes, scatter.
    float bn[4];
#pragma unroll
    for (int n = 0; n < 4; ++n) bn[n] = bias[n0 + wc * 64 + n * 16 + r16];

    if (z < 2) {
        unsigned short* ph = (unsigned short*)(ws + (z == 0 ? P_QPH : P_KPH));
        unsigned short* pl = (unsigned short*)(ws + (z == 0 ? P_QPL : P_KPL));
#pragma unroll
        for (int m = 0; m < 4; ++m)
#pragma unroll
            for (int n = 0; n < 4; ++n) {
                const int col = n0 + wc * 64 + n * 16 + r16;
                const int hh = col >> 6, d = col & 63;
#pragma unroll
                for (int r = 0; r < 4; ++r) {
                    const int tok = m0 + wr * 64 + m * 16 + g * 4 + r;
                    const int s = tok >> 1, b = tok & 1;
                    unsigned short vh, vl;
                    split1(acc[m][n][r] + bn[n], vh, vl);
                    const size_t idx = ((size_t)((b * 16 + hh) * 2048 + s)) * 64 + d;
                    ph[idx] = vh; pl[idx] = vl;
                }
            }
    } else {
        // V: write TRANSPOSED planes [B,H,D,S]; pack (s, s+1) pairs as ushort2.
        unsigned short* ph = (unsigned short*)(ws + P_VTH);
        unsigned short* pl = (unsigned short*)(ws + P_VTL);
#pragma unroll
        for (int m = 0; m < 4; ++m)
#pragma unroll
            for (int n = 0; n < 4; ++n) {
                const int col = n0 + wc * 64 + n * 16 + r16;
                const int hh = col >> 6, d = col & 63;
                const int tok0 = m0 + wr * 64 + m * 16 + g * 4;   // always even, div by 4
                const int s0 = tok0 >> 1;
                unsigned short vh[4], vl[4];
#pragma unroll
                for (int r = 0; r < 4; ++r) split1(acc[m][n][r] + bn[n], vh[r], vl[r]);
                // r: 0->(s0,b0) 1->(s0,b1) 2->(s0+1,b0) 3->(s0+1,b1)
                const size_t i0 = ((size_t)((0  + hh) * 64 + d)) * 2048 + s0;  // b=0
                const size_t i1 = ((size_t)((16 + hh) * 64 + d)) * 2048 + s0;  // b=1
                ushort2 u;
                u.x = vh[0]; u.y = vh[2]; *(ushort2*)&ph[i0] = u;
                u.x = vh[1]; u.y = vh[3]; *(ushort2*)&ph[i1] = u;
                u.x = vl[0]; u.y = vl[2]; *(ushort2*)&pl[i0] = u;
                u.x = vl[1]; u.y = vl[3]; *(ushort2*)&pl[i1] = u;
            }
    }
}

// ---------------------------------------------------------------------------
// Out projection GEMM from planes: out = ao @ Wo^T + bo. 64x128 tile (512
// blocks = 2/CU), BK=32, 4 waves 2x2 (wave tile 32x64), 3-pass split MFMA.
// ---------------------------------------------------------------------------
__global__ __launch_bounds__(256, 2) void gemm_out_planes(
    const float* __restrict__ bo, const unsigned char* __restrict__ ws,
    float* __restrict__ out)
{
    __shared__ unsigned short AH[2048], AL[2048], WH[4096], WL[4096];  // A 64x32, W 128x32

    const unsigned char* aph = ws + P_AOH;
    const unsigned char* apl = ws + P_AOL;
    const unsigned char* wph = ws + P_WOH;
    const unsigned char* wpl = ws + P_WOL;

    const int t = threadIdx.x, lid = t & 63, w = t >> 6;
    const int wr = w >> 1, wc = w & 1, g = lid >> 4, r16 = lid & 15;
    const int m0 = blockIdx.x * 64, n0 = blockIdx.y * 128;
    const int lrow = lid >> 2;
    const int cA = (lid & 3) ^ (lrow & 3);

    int offA[2], offW[4];
#pragma unroll
    for (int m = 0; m < 2; ++m)
        offA[m] = (wr * 32 + m * 16 + r16) * 32 + ((g ^ (r16 & 3)) << 3);
#pragma unroll
    for (int n = 0; n < 4; ++n)
        offW[n] = (wc * 64 + n * 16 + r16) * 32 + ((g ^ (r16 & 3)) << 3);

    f32x4 acc[2][4];
    const f32x4 zero = {0.f, 0.f, 0.f, 0.f};
#pragma unroll
    for (int m = 0; m < 2; ++m)
#pragma unroll
        for (int n = 0; n < 4; ++n) acc[m][n] = zero;

    for (int kt = 0; kt < 1024; kt += 32) {
        __syncthreads();
        {
            const int ra = m0 + w * 16 + lrow;
            const size_t ab = (size_t)ra * 2048 + (size_t)kt * 2 + (size_t)cA * 16;
            gl16(aph + ab, &AH[(w * 16) * 32]);
            gl16(apl + ab, &AL[(w * 16) * 32]);
        }
#pragma unroll
        for (int i = 0; i < 2; ++i) {
            const int rw = n0 + w * 32 + i * 16 + lrow;
            const size_t wb = (size_t)rw * 2048 + (size_t)kt * 2 + (size_t)cA * 16;
            gl16(wph + wb, &WH[(w * 32 + i * 16) * 32]);
            gl16(wpl + wb, &WL[(w * 32 + i * 16) * 32]);
        }
        __syncthreads();

        bf16x8 ah[2], al[2], whf[4], wlf[4];
#pragma unroll
        for (int m = 0; m < 2; ++m) {
            ah[m] = *(const bf16x8*)&AH[offA[m]];
            al[m] = *(const bf16x8*)&AL[offA[m]];
        }
#pragma unroll
        for (int n = 0; n < 4; ++n) {
            whf[n] = *(const bf16x8*)&WH[offW[n]];
            wlf[n] = *(const bf16x8*)&WL[offW[n]];
        }
#pragma unroll
        for (int m = 0; m < 2; ++m)
#pragma unroll
            for (int n = 0; n < 4; ++n) {
                acc[m][n] = __builtin_amdgcn_mfma_f32_16x16x32_bf16(ah[m], whf[n], acc[m][n], 0, 0, 0);
                acc[m][n] = __builtin_amdgcn_mfma_f32_16x16x32_bf16(ah[m], wlf[n], acc[m][n], 0, 0, 0);
                acc[m][n] = __builtin_amdgcn_mfma_f32_16x16x32_bf16(al[m], whf[n], acc[m][n], 0, 0, 0);
            }
    }

    float bn[4];
#pragma unroll
    for (int n = 0; n < 4; ++n) bn[n] = bo[n0 + wc * 64 + n * 16 + r16];
#pragma unroll
    for (int m = 0; m < 2; ++m)
#pragma unroll
        for (int n = 0; n < 4; ++n) {
            const int col = n0 + wc * 64 + n * 16 + r16;
#pragma unroll
            for (int r = 0; r < 4; ++r) {
                const int row = m0 + wr * 32 + m * 16 + g * 4 + r;
                out[(size_t)row * 1024 + col] = acc[m][n][r] + bn[n];
            }
        }
}

// ---------------------------------------------------------------------------
// Causal flash attention, split-bf16 MFMA, plane inputs, gload_lds staging,
// double-buffered K/V^T tiles with early-issue prefetch. 80KB LDS, 2 blk/CU.
// Block = 4 waves; q-tile pair (p, 31-p) per block -> 33 k-tiles each.
// ---------------------------------------------------------------------------
__global__ __launch_bounds__(256, 2) void attn_fwd(unsigned char* __restrict__ ws)
{
    // buf b (b=0,1): KH = b*16384, KL = +4096, VTH = +8192, VTL = +12288
    // PQH = 32768, PQL = 36864  (Q at pass start, then P)
    __shared__ unsigned short sm[40960];   // 80 KB

    const int t = threadIdx.x, lid = t & 63, w = t >> 6;
    const int g = lid >> 4, r16 = lid & 15;
    const int bh = blockIdx.y;
    const int b = bh >> 4, h = bh & 15;

    const unsigned char* qhp  = ws + P_QPH + (size_t)bh * 262144;
    const unsigned char* qlp  = ws + P_QPL + (size_t)bh * 262144;
    const unsigned char* khp  = ws + P_KPH + (size_t)bh * 262144;
    const unsigned char* klp  = ws + P_KPL + (size_t)bh * 262144;
    const unsigned char* vthp = ws + P_VTH + (size_t)bh * 262144;
    const unsigned char* vtlp = ws + P_VTL + (size_t)bh * 262144;
    unsigned short* aoh = (unsigned short*)(ws + P_AOH);
    unsigned short* aol = (unsigned short*)(ws + P_AOL);

    const int lrow = lid >> 3;            // 0..7
    const int cK = (lid & 7) ^ lrow;      // swizzled source chunk
    const float scale = 0.125f;           // 1/sqrt(64)

    // fragment read offsets (ushort units), 128B rows with XOR-16B-slot swizzle
    int offF[4][2], offQ[2], offP[4][4];
#pragma unroll
    for (int nf = 0; nf < 4; ++nf)
#pragma unroll
        for (int ks = 0; ks < 2; ++ks)
            offF[nf][ks] = (nf * 16 + r16) * 64 + (((ks * 4 + g) ^ (r16 & 7)) << 3);
#pragma unroll
    for (int ks = 0; ks < 2; ++ks)
        offQ[ks] = (w * 16 + r16) * 64 + (((ks * 4 + g) ^ (r16 & 7)) << 3);
#pragma unroll
    for (int nf = 0; nf < 4; ++nf)
#pragma unroll
        for (int r = 0; r < 4; ++r) {
            const int rp = w * 16 + g * 4 + r;
            offP[nf][r] = rp * 64 + (((nf * 2 + (r16 >> 3)) ^ (rp & 7)) << 3) + (r16 & 7);
        }

    auto stage_kv = [&](int bsel, int tt) {
#pragma unroll
        for (int i = 0; i < 2; ++i) {
            const int r = w * 16 + i * 8 + lrow;
            const int db = bsel * 16384 + (w * 16 + i * 8) * 64;
            const size_t kb = (size_t)(tt * 64 + r) * 128 + (size_t)cK * 16;
            gl16(khp + kb, &sm[db]);
            gl16(klp + kb, &sm[db + 4096]);
            const size_t vb = (size_t)r * 4096 + (size_t)tt * 128 + (size_t)cK * 16;
            gl16(vthp + vb, &sm[db + 8192]);
            gl16(vtlp + vb, &sm[db + 12288]);
        }
    };

    const f32x4 zero = {0.f, 0.f, 0.f, 0.f};

    for (int pass = 0; pass < 2; ++pass) {
        const int qt = (pass == 0) ? blockIdx.x : 31 - blockIdx.x;
        const int q0 = qt * 64;

        // stage Q (into PQ) + K/V^T tile 0 (into buf 0); one drain barrier
#pragma unroll
        for (int i = 0; i < 2; ++i) {
            const int r = w * 16 + i * 8 + lrow;
            const size_t qb = (size_t)(q0 + r) * 128 + (size_t)cK * 16;
            gl16(qhp + qb, &sm[32768 + (w * 16 + i * 8) * 64]);
            gl16(qlp + qb, &sm[36864 + (w * 16 + i * 8) * 64]);
        }
        stage_kv(0, 0);
        __syncthreads();

        bf16x8 qh[2], ql[2];
#pragma unroll
        for (int ks = 0; ks < 2; ++ks) {
            qh[ks] = *(const bf16x8*)&sm[32768 + offQ[ks]];
            ql[ks] = *(const bf16x8*)&sm[36864 + offQ[ks]];
        }

        f32x4 oacc[4];
        float m_r[4], l_r[4];
#pragma unroll
        for (int i = 0; i < 4; ++i) { oacc[i] = zero; m_r[i] = NEG_BIG; l_r[i] = 0.f; }

        for (int tt = 0; tt <= qt; ++tt) {
            const int bb = (tt & 1) * 16384;
            const int k0 = tt * 64;
            if (tt < qt) stage_kv((tt & 1) ^ 1, tt + 1);  // prefetch flies under compute

            // ---- QK^T (3-pass) ----
            f32x4 sacc[4];
#pragma unroll
            for (int nf = 0; nf < 4; ++nf) sacc[nf] = zero;
#pragma unroll
            for (int nf = 0; nf < 4; ++nf)
#pragma unroll
                for (int ks = 0; ks < 2; ++ks) {
                    bf16x8 kh = *(const bf16x8*)&sm[bb + offF[nf][ks]];
                    bf16x8 kl = *(const bf16x8*)&sm[bb + 4096 + offF[nf][ks]];
                    sacc[nf] = __builtin_amdgcn_mfma_f32_16x16x32_bf16(qh[ks], kh, sacc[nf], 0, 0, 0);
                    sacc[nf] = __builtin_amdgcn_mfma_f32_16x16x32_bf16(qh[ks], kl, sacc[nf], 0, 0, 0);
                    sacc[nf] = __builtin_amdgcn_mfma_f32_16x16x32_bf16(ql[ks], kh, sacc[nf], 0, 0, 0);
                }

            // ---- softmax (fp32; lane rows q = q0 + w*16 + g*4 + r) ----
            float rm[4] = {NEG_BIG, NEG_BIG, NEG_BIG, NEG_BIG};
#pragma unroll
            for (int nf = 0; nf < 4; ++nf) {
                const int k_abs = k0 + nf * 16 + r16;
#pragma unroll
                for (int r = 0; r < 4; ++r) {
                    const int q_abs = q0 + w * 16 + g * 4 + r;
                    float val = sacc[nf][r] * scale;
                    if (k_abs > q_abs) val = NEG_BIG;
                    sacc[nf][r] = val;
                    rm[r] = fmaxf(rm[r], val);
                }
            }
#pragma unroll
            for (int off = 1; off < 16; off <<= 1)
#pragma unroll
                for (int r = 0; r < 4; ++r)
                    rm[r] = fmaxf(rm[r], __shfl_xor(rm[r], off, 64));

            float scf[4];
#pragma unroll
            for (int r = 0; r < 4; ++r) {
                const float mn = fmaxf(m_r[r], rm[r]);
                scf[r] = __expf(m_r[r] - mn);
                m_r[r] = mn;
            }

            float pv4[4][4];
            float rs[4] = {0.f, 0.f, 0.f, 0.f};
#pragma unroll
            for (int nf = 0; nf < 4; ++nf)
#pragma unroll
                for (int r = 0; r < 4; ++r) {
                    const float p = __expf(sacc[nf][r] - m_r[r]);  // masked -> 0
                    pv4[nf][r] = p;
                    rs[r] += p;
                }
#pragma unroll
            for (int off = 1; off < 16; off <<= 1)
#pragma unroll
                for (int r = 0; r < 4; ++r)
                    rs[r] += __shfl_xor(rs[r], off, 64);

#pragma unroll
            for (int r = 0; r < 4; ++r) {
                l_r[r] = l_r[r] * scf[r] + rs[r];
#pragma unroll
                for (int nf = 0; nf < 4; ++nf) oacc[nf][r] *= scf[r];
            }

            // ---- P (hi/lo) to own wave's PQ rows (same-wave, no barrier) ----
#pragma unroll
            for (int nf = 0; nf < 4; ++nf)
#pragma unroll
                for (int r = 0; r < 4; ++r) {
                    unsigned short h1, l1;
                    split1(pv4[nf][r], h1, l1);
                    sm[32768 + offP[nf][r]] = h1;
                    sm[36864 + offP[nf][r]] = l1;
                }

            // ---- O += P @ V (3-pass) ----
#pragma unroll
            for (int ks = 0; ks < 2; ++ks) {
                bf16x8 pah = *(const bf16x8*)&sm[32768 + offQ[ks]];
                bf16x8 pal = *(const bf16x8*)&sm[36864 + offQ[ks]];
#pragma unroll
                for (int nf = 0; nf < 4; ++nf) {
                    bf16x8 vh = *(const bf16x8*)&sm[bb + 8192 + offF[nf][ks]];
                    bf16x8 vl = *(const bf16x8*)&sm[bb + 12288 + offF[nf][ks]];
                    oacc[nf] = __builtin_amdgcn_mfma_f32_16x16x32_bf16(pah, vh, oacc[nf], 0, 0, 0);
                    oacc[nf] = __builtin_amdgcn_mfma_f32_16x16x32_bf16(pah, vl, oacc[nf], 0, 0, 0);
                    oacc[nf] = __builtin_amdgcn_mfma_f32_16x16x32_bf16(pal, vh, oacc[nf], 0, 0, 0);
                }
            }
            __syncthreads();  // drain prefetch + protect buffers/PQ
        }

        // ---- epilogue: O/l -> ao hi/lo planes [S,B,E] ----
        float inv[4];
#pragma unroll
        for (int r = 0; r < 4; ++r) inv[r] = 1.0f / l_r[r];
#pragma unroll
        for (int nf = 0; nf < 4; ++nf) {
            const int d = nf * 16 + r16;
#pragma unroll
            for (int r = 0; r < 4; ++r) {
                const int s = q0 + w * 16 + g * 4 + r;
                unsigned short hh, ll;
                split1(oacc[nf][r] * inv[r], hh, ll);
                const size_t idx = (size_t)(s * 2 + b) * 1024 + h * 64 + d;
                aoh[idx] = hh; aol[idx] = ll;
            }
        }
    }
}

// ---------------------------------------------------------------------------
extern "C" void kernel_launch(void* const* d_in, const int* in_sizes, int n_in,
                              void* d_out, int out_size, void* d_ws, size_t ws_size,
                              hipStream_t stream)
{
    const float* query = (const float*)d_in[0];
    const float* key   = (const float*)d_in[1];
    const float* value = (const float*)d_in[2];
    const float* Wq = (const float*)d_in[3];  const float* bq = (const float*)d_in[4];
    const float* Wk = (const float*)d_in[5];  const float* bk = (const float*)d_in[6];
    const float* Wv = (const float*)d_in[7];  const float* bv = (const float*)d_in[8];
    const float* Wo = (const float*)d_in[9];  const float* bo = (const float*)d_in[10];
    float* out = (float*)d_out;
    unsigned char* ws = (unsigned char*)d_ws;
    (void)ws_size; (void)in_sizes; (void)n_in; (void)out_size;

    const dim3 tb(256);

    split_planes<<<dim3(4096, 7), tb, 0, stream>>>(query, key, value, Wq, Wk, Wv, Wo, ws);
    gemm_qkv_planes<<<dim3(32, 8, 3), tb, 0, stream>>>(bq, bk, bv, ws);
    attn_fwd<<<dim3(16, 32), tb, 0, stream>>>(ws);
    gemm_out_planes<<<dim3(64, 8), tb, 0, stream>>>(bo, ws, out);
}